// Round 1
// 129.353 us; speedup vs baseline: 1.0184x; 1.0184x over previous
//
#include <hip/hip_runtime.h>

// Elman RNN, B=262144, IN=32, H=16, T=30, OUT=1, fp32 in/out.
// Round 6: shared-reciprocal tanh.
// Rounds 3-4 proved chain/ILP changes are neutral; counter fit (VALUBusy
// 51% ~= 130 VALU-class cycles/step) says trans ops (~13 cy issue each on
// wave64) dominate issue. So cut trans ops: the 4 per-lane reciprocals of
// tanh batch into ONE v_rcp via the product trick:
//   d_i = 1+e_i in [1, 2^21] -> r = rcp(d0 d1 d2 d3) (<= 2^84, no ovf)
//   1/d0 = (r*m23)*d1, etc.  (full-rate muls replace 3 trans rcps)
// Per step: 8 trans + 11 VALU  ->  5 trans + 20 VALU  (-17% issue cycles).
// Extra rounding ~4 ulp fp32 — invisible under the fp16-state error floor.
//  - Recurrence via ONE fp16 MFMA (16x16x16_f16); xproj exact fp32 in C.
//  - fc head: W_fc hi+lo as rows 0/1 of ONE A-matrix -> 1 MFMA.
//  - State repack: v_cvt_pkrtz (2 floats -> packed fp16 pair, 1 op).
// Layout invariant (verified rounds 2-4): for 16x16x16 MFMA the B-fragment
// layout == C/D layout, so tanh(acc) repacks elementwise into the next B
// operand — the state stays transposed (S = H^T), never crosses lanes.

#define T_STEPS 30
#define BLOCK   256
#define SCALE   2.8853900817779268f   // 2*log2(e)

typedef _Float16 v4h __attribute__((ext_vector_type(4)));
typedef __fp16   v2fp __attribute__((ext_vector_type(2)));
typedef float    v4f __attribute__((ext_vector_type(4)));

struct h4 { v2fp lo, hi; };

__global__ __launch_bounds__(BLOCK, 8) void rnn_mfma(
    const float* __restrict__ x,     // [B, 32]
    const float* __restrict__ W_ih,  // [16, 32]
    const float* __restrict__ W_hh,  // [16, 16]
    const float* __restrict__ b_ih,  // [16]
    const float* __restrict__ b_hh,  // [16]
    const float* __restrict__ W_fc,  // [1, 16]
    const float* __restrict__ b_fc,  // [1]
    float* __restrict__ out)         // [B, 30]
{
    __shared__ float tmp[64 * T_STEPS];   // 64 rows/block x 30 steps

    const int tid  = threadIdx.x;
    const int w    = tid >> 6;        // wave in block (0..3), 16 rows each
    const int lane = tid & 63;
    const int r    = lane & 15;       // MFMA row index (batch row / A-row)
    const int q    = lane >> 4;       // quad
    const int j0   = 4 * q;

    const size_t row = (size_t)blockIdx.x * 64 + (size_t)w * 16 + r;

    // ---- xproj (exact fp32), C-fragment order: lane holds rows j=4q+i, col r.
    float a0 = b_ih[j0 + 0] + b_hh[j0 + 0];
    float a1 = b_ih[j0 + 1] + b_hh[j0 + 1];
    float a2 = b_ih[j0 + 2] + b_hh[j0 + 2];
    float a3 = b_ih[j0 + 3] + b_hh[j0 + 3];
    {
        const float4* xrow = (const float4*)(x + row * 32);
#pragma unroll
        for (int c4 = 0; c4 < 8; ++c4) {
            float4 xv = xrow[c4];
            const float4 w0 = *(const float4*)(W_ih + (j0 + 0) * 32 + c4 * 4);
            const float4 w1 = *(const float4*)(W_ih + (j0 + 1) * 32 + c4 * 4);
            const float4 w2 = *(const float4*)(W_ih + (j0 + 2) * 32 + c4 * 4);
            const float4 w3 = *(const float4*)(W_ih + (j0 + 3) * 32 + c4 * 4);
            a0 = fmaf(w0.x, xv.x, fmaf(w0.y, xv.y, fmaf(w0.z, xv.z, fmaf(w0.w, xv.w, a0))));
            a1 = fmaf(w1.x, xv.x, fmaf(w1.y, xv.y, fmaf(w1.z, xv.z, fmaf(w1.w, xv.w, a1))));
            a2 = fmaf(w2.x, xv.x, fmaf(w2.y, xv.y, fmaf(w2.z, xv.z, fmaf(w2.w, xv.w, a2))));
            a3 = fmaf(w3.x, xv.x, fmaf(w3.y, xv.y, fmaf(w3.z, xv.z, fmaf(w3.w, xv.w, a3))));
        }
    }
    // Pre-scaled by 2*log2e: tanh chain starts directly at exp2.
    const v4f xpv = {a0 * SCALE, a1 * SCALE, a2 * SCALE, a3 * SCALE};

    // ---- W_hh A-fragment in fp16 (RNE): A[m=r][k=4q+i] = SCALE*W_hh[r][4q+i]
    v4h whh;
    {
        float4 wr = *(const float4*)(W_hh + r * 16 + 4 * q);
        whh[0] = (_Float16)(wr.x * SCALE);
        whh[1] = (_Float16)(wr.y * SCALE);
        whh[2] = (_Float16)(wr.z * SCALE);
        whh[3] = (_Float16)(wr.w * SCALE);
    }

    // ---- fc A-fragment (UNSCALED): row0 = fp16(W_fc), row1 = fp16 residual
    v4h afc;
#pragma unroll
    for (int i = 0; i < 4; ++i) {
        float wv = W_fc[4 * q + i];
        _Float16 hi = (_Float16)wv;
        _Float16 lo = (_Float16)(wv - (float)hi);
        afc[i] = (r == 0) ? hi : ((r == 1) ? lo : (_Float16)0.0f);
    }
    const float bfc = b_fc[0];
    const v4f zfc = {(q == 0) ? bfc : 0.0f, 0.0f, 0.0f, 0.0f};

    // ---- state S = H^T in fp16 (B-frag == C/D-frag layout)
    v4h s = {(_Float16)0.0f, (_Float16)0.0f, (_Float16)0.0f, (_Float16)0.0f};

    float* myout = &tmp[(w * 16 + r) * T_STEPS];   // lanes 0..15 write

#pragma unroll
    for (int t = 0; t < T_STEPS; ++t) {
        // preact (pre-scaled) = SCALE*Xp^T + (SCALE*W_hh)*S — one fp16 MFMA
        v4f acc = __builtin_amdgcn_mfma_f32_16x16x16f16(whh, s, xpv, 0, 0, 0);

        // tanh = 1 - 2/(1+e), e = exp2(preact_scaled).
        // 4 independent exp2 (trans), then ONE rcp shared across the 4
        // denominators via the product trick (full-rate muls recover each
        // reciprocal). 5 trans + 17 VALU, was 8 trans + 8 VALU.
        float e0 = __builtin_amdgcn_exp2f(acc[0]);
        float e1 = __builtin_amdgcn_exp2f(acc[1]);
        float e2 = __builtin_amdgcn_exp2f(acc[2]);
        float e3 = __builtin_amdgcn_exp2f(acc[3]);
        float d0 = 1.0f + e0;
        float d1 = 1.0f + e1;
        float d2 = 1.0f + e2;
        float d3 = 1.0f + e3;
        float m01 = d0 * d1;
        float m23 = d2 * d3;
        float rr  = __builtin_amdgcn_rcpf(m01 * m23);
        float r01 = rr * m23;          // ~ 1/(d0*d1)
        float r23 = rr * m01;          // ~ 1/(d2*d3)
        float h0 = fmaf(-2.0f, r01 * d1, 1.0f);   // 1 - 2/d0
        float h1 = fmaf(-2.0f, r01 * d0, 1.0f);   // 1 - 2/d1
        float h2 = fmaf(-2.0f, r23 * d3, 1.0f);   // 1 - 2/d2
        float h3 = fmaf(-2.0f, r23 * d2, 1.0f);   // 1 - 2/d3

        // repack state: 2 x v_cvt_pkrtz (RTZ, |err| <= 1 ulp ~ 2^-10)
        h4 p;
        p.lo = __builtin_amdgcn_cvt_pkrtz(h0, h1);
        p.hi = __builtin_amdgcn_cvt_pkrtz(h2, h3);
        s = __builtin_bit_cast(v4h, p);

        // fc head: one MFMA, rows 0(hi)+1(lo); leaf of the t-chain
        v4f f = __builtin_amdgcn_mfma_f32_16x16x16f16(afc, s, zfc, 0, 0, 0);

        if (lane < 16)
            myout[t] = f[0] + f[1];
    }

    __syncthreads();

    // ---- coalesced writeout: block region out[block*64..+64)[0..30) contiguous
    float* oblk = out + (size_t)blockIdx.x * (64 * T_STEPS);
    for (int idx = tid; idx < 64 * T_STEPS; idx += BLOCK)
        oblk[idx] = tmp[idx];
}

extern "C" void kernel_launch(void* const* d_in, const int* in_sizes, int n_in,
                              void* d_out, int out_size, void* d_ws, size_t ws_size,
                              hipStream_t stream) {
    // inputs: x, T, W_ih, W_hh, b_ih, b_hh, W_fc, b_fc
    const float* x    = (const float*)d_in[0];
    const float* W_ih = (const float*)d_in[2];
    const float* W_hh = (const float*)d_in[3];
    const float* b_ih = (const float*)d_in[4];
    const float* b_hh = (const float*)d_in[5];
    const float* W_fc = (const float*)d_in[6];
    const float* b_fc = (const float*)d_in[7];
    float* out = (float*)d_out;

    const int B = in_sizes[0] / 32;      // 262144
    const int grid = B / 64;             // 4096 blocks, 64 rows each

    rnn_mfma<<<grid, BLOCK, 0, stream>>>(x, W_ih, W_hh, b_ih, b_hh, W_fc, b_fc, out);
}

// Round 2
// 116.076 us; speedup vs baseline: 1.1349x; 1.1144x over previous
//
#include <hip/hip_runtime.h>

// Elman RNN, B=262144, IN=32, H=16, T=30, OUT=1, fp32 in/out.
// Round 7: MFMA-ize the xproj prologue + fc pipelining + paired LDS writes.
// Issue-cycle audit (rounds 5-6 A/B fit: trans ~6.5 cy, VALU ~2 cy issue per
// wave64 op): inner loop ~65 cy/step is near floor for 1 exp + shared-rcp
// tanh; the biggest remaining block was the PROLOGUE: 128 scalar FMAs + 40
// vector loads (~340 cy/wave ~ 15% of issue) doing matmul-shaped work on the
// saturated VALU pipe while MfmaUtil sits at 11%.
//  - xproj via 6 chained 16x16x16_f16 MFMAs, split-precision:
//      SCALE*W_ih * x^T ~= Whi*xhi + Whi*xlo + Wlo*xhi   (per K-half)
//    residual = sum Wlo*xlo ~ 1e-6 << fp16-state noise (~1e-3): absmax safe.
//    Uses the SAME verified A/B fragment layouts as whh/s (A[m=lane&15][k=4q+e],
//    B[k=4q+e][n=lane&15]); SCALE folded into W/bias fragments (frees 4 muls).
//  - fc head pipelined: f consumed 1-2 iterations after its MFMA (waitcnt off
//    the t-chain); outputs written as ONE float2 LDS write per 2 steps
//    (halves ds_write + exec-mask traffic).
//  - Recurrence loop body unchanged from round 6 (1 fp16 MFMA + 4 exp2 +
//    shared rcp + cvt_pkrtz repack).
// Layout invariant (verified rounds 2-4): for 16x16x16 MFMA the B-fragment
// layout == C/D layout, so tanh(acc) repacks elementwise into the next B
// operand — the state stays transposed (S = H^T), never crosses lanes.

#define T_STEPS 30
#define BLOCK   256
#define SCALE   2.8853900817779268f   // 2*log2(e)

typedef _Float16 v4h __attribute__((ext_vector_type(4)));
typedef __fp16   v2fp __attribute__((ext_vector_type(2)));
typedef float    v4f __attribute__((ext_vector_type(4)));

struct h4 { v2fp lo, hi; };

static __device__ __forceinline__ v4h pack4(float a, float b, float c, float d) {
    h4 p;
    p.lo = __builtin_amdgcn_cvt_pkrtz(a, b);
    p.hi = __builtin_amdgcn_cvt_pkrtz(c, d);
    return __builtin_bit_cast(v4h, p);
}

__global__ __launch_bounds__(BLOCK, 8) void rnn_mfma(
    const float* __restrict__ x,     // [B, 32]
    const float* __restrict__ W_ih,  // [16, 32]
    const float* __restrict__ W_hh,  // [16, 16]
    const float* __restrict__ b_ih,  // [16]
    const float* __restrict__ b_hh,  // [16]
    const float* __restrict__ W_fc,  // [1, 16]
    const float* __restrict__ b_fc,  // [1]
    float* __restrict__ out)         // [B, 30]
{
    __shared__ float tmp[64 * T_STEPS];   // 64 rows/block x 30 steps

    const int tid  = threadIdx.x;
    const int w    = tid >> 6;        // wave in block (0..3), 16 rows each
    const int lane = tid & 63;
    const int r    = lane & 15;       // MFMA row index (batch row / A-row)
    const int q    = lane >> 4;       // quad
    const int j0   = 4 * q;

    const size_t row = (size_t)blockIdx.x * 64 + (size_t)w * 16 + r;

    // ---- xproj via split-precision MFMA chain.
    // A-frag (m=lane&15, k=4q+e): lane holds SCALE*W_ih[r][kh*16 + 4q+e].
    // B-frag (k=4q+e, n=lane&15): lane holds x[row][kh*16 + 4q+e].
    // C-frag (row=4q+i, col=lane&15): bias SCALE*(b_ih+b_hh)[4q+i].
    v4f xpv;
    {
        const float4 x0 = *(const float4*)(x + row * 32 + 4 * q);
        const float4 x1 = *(const float4*)(x + row * 32 + 16 + 4 * q);
        float4 w0 = *(const float4*)(W_ih + r * 32 + 4 * q);
        float4 w1 = *(const float4*)(W_ih + r * 32 + 16 + 4 * q);
        w0.x *= SCALE; w0.y *= SCALE; w0.z *= SCALE; w0.w *= SCALE;
        w1.x *= SCALE; w1.y *= SCALE; w1.z *= SCALE; w1.w *= SCALE;

        v4h xh0 = pack4(x0.x, x0.y, x0.z, x0.w);
        v4h xh1 = pack4(x1.x, x1.y, x1.z, x1.w);
        v4h wh0 = pack4(w0.x, w0.y, w0.z, w0.w);
        v4h wh1 = pack4(w1.x, w1.y, w1.z, w1.w);
        v4h xl0 = pack4(x0.x - (float)xh0[0], x0.y - (float)xh0[1],
                        x0.z - (float)xh0[2], x0.w - (float)xh0[3]);
        v4h xl1 = pack4(x1.x - (float)xh1[0], x1.y - (float)xh1[1],
                        x1.z - (float)xh1[2], x1.w - (float)xh1[3]);
        v4h wl0 = pack4(w0.x - (float)wh0[0], w0.y - (float)wh0[1],
                        w0.z - (float)wh0[2], w0.w - (float)wh0[3]);
        v4h wl1 = pack4(w1.x - (float)wh1[0], w1.y - (float)wh1[1],
                        w1.z - (float)wh1[2], w1.w - (float)wh1[3]);

        const float4 bi = *(const float4*)(b_ih + j0);
        const float4 bh = *(const float4*)(b_hh + j0);
        v4f c = {SCALE * (bi.x + bh.x), SCALE * (bi.y + bh.y),
                 SCALE * (bi.z + bh.z), SCALE * (bi.w + bh.w)};

        xpv = __builtin_amdgcn_mfma_f32_16x16x16f16(wh0, xh0, c,   0, 0, 0);
        xpv = __builtin_amdgcn_mfma_f32_16x16x16f16(wh1, xh1, xpv, 0, 0, 0);
        xpv = __builtin_amdgcn_mfma_f32_16x16x16f16(wh0, xl0, xpv, 0, 0, 0);
        xpv = __builtin_amdgcn_mfma_f32_16x16x16f16(wh1, xl1, xpv, 0, 0, 0);
        xpv = __builtin_amdgcn_mfma_f32_16x16x16f16(wl0, xh0, xpv, 0, 0, 0);
        xpv = __builtin_amdgcn_mfma_f32_16x16x16f16(wl1, xh1, xpv, 0, 0, 0);
    }

    // ---- W_hh A-fragment in fp16 (RNE): A[m=r][k=4q+i] = SCALE*W_hh[r][4q+i]
    v4h whh;
    {
        float4 wr = *(const float4*)(W_hh + r * 16 + 4 * q);
        whh[0] = (_Float16)(wr.x * SCALE);
        whh[1] = (_Float16)(wr.y * SCALE);
        whh[2] = (_Float16)(wr.z * SCALE);
        whh[3] = (_Float16)(wr.w * SCALE);
    }

    // ---- fc A-fragment (UNSCALED): row0 = fp16(W_fc), row1 = fp16 residual
    v4h afc;
#pragma unroll
    for (int i = 0; i < 4; ++i) {
        float wv = W_fc[4 * q + i];
        _Float16 hi = (_Float16)wv;
        _Float16 lo = (_Float16)(wv - (float)hi);
        afc[i] = (r == 0) ? hi : ((r == 1) ? lo : (_Float16)0.0f);
    }
    const float bfc = b_fc[0];
    const v4f zfc = {(q == 0) ? bfc : 0.0f, 0.0f, 0.0f, 0.0f};

    // ---- state S = H^T in fp16 (B-frag == C/D-frag layout)
    v4h s = {(_Float16)0.0f, (_Float16)0.0f, (_Float16)0.0f, (_Float16)0.0f};

    float* myout = &tmp[(w * 16 + r) * T_STEPS];   // lanes 0..15 write

    v4f fe, fo;   // pipelined fc results (even / odd step)

#pragma unroll
    for (int t = 0; t < T_STEPS; ++t) {
        // preact (pre-scaled) = SCALE*Xp^T + (SCALE*W_hh)*S — one fp16 MFMA
        v4f acc = __builtin_amdgcn_mfma_f32_16x16x16f16(whh, s, xpv, 0, 0, 0);

        // tanh = 1 - 2/(1+e), e = exp2(preact_scaled).
        // 4 independent exp2 (trans) + ONE shared rcp (product trick).
        float e0 = __builtin_amdgcn_exp2f(acc[0]);
        float e1 = __builtin_amdgcn_exp2f(acc[1]);
        float e2 = __builtin_amdgcn_exp2f(acc[2]);
        float e3 = __builtin_amdgcn_exp2f(acc[3]);
        float d0 = 1.0f + e0;
        float d1 = 1.0f + e1;
        float d2 = 1.0f + e2;
        float d3 = 1.0f + e3;
        float m01 = d0 * d1;
        float m23 = d2 * d3;
        float rr  = __builtin_amdgcn_rcpf(m01 * m23);
        float r01 = rr * m23;          // ~ 1/(d0*d1)
        float r23 = rr * m01;          // ~ 1/(d2*d3)
        float h0 = fmaf(-2.0f, r01 * d1, 1.0f);   // 1 - 2/d0
        float h1 = fmaf(-2.0f, r01 * d0, 1.0f);   // 1 - 2/d1
        float h2 = fmaf(-2.0f, r23 * d3, 1.0f);   // 1 - 2/d2
        float h3 = fmaf(-2.0f, r23 * d2, 1.0f);   // 1 - 2/d3

        // repack state: 2 x v_cvt_pkrtz (RTZ, |err| <= 1 ulp ~ 2^-10)
        s = pack4(h0, h1, h2, h3);

        // fc head: one MFMA, consumed 1-2 iterations later (waitcnt off the
        // chain); two steps' outputs merge into one float2 LDS write.
        if ((t & 1) == 0) {
            if (t >= 2 && lane < 16) {
                float2 g;
                g.x = fe[0] + fe[1];
                g.y = fo[0] + fo[1];
                *(float2*)(myout + (t - 2)) = g;
            }
            fe = __builtin_amdgcn_mfma_f32_16x16x16f16(afc, s, zfc, 0, 0, 0);
        } else {
            fo = __builtin_amdgcn_mfma_f32_16x16x16f16(afc, s, zfc, 0, 0, 0);
        }
    }
    if (lane < 16) {
        float2 g;
        g.x = fe[0] + fe[1];
        g.y = fo[0] + fo[1];
        *(float2*)(myout + (T_STEPS - 2)) = g;
    }

    __syncthreads();

    // ---- coalesced writeout: block region out[block*64..+64)[0..30) contiguous
    float* oblk = out + (size_t)blockIdx.x * (64 * T_STEPS);
    for (int idx = tid; idx < 64 * T_STEPS; idx += BLOCK)
        oblk[idx] = tmp[idx];
}

extern "C" void kernel_launch(void* const* d_in, const int* in_sizes, int n_in,
                              void* d_out, int out_size, void* d_ws, size_t ws_size,
                              hipStream_t stream) {
    // inputs: x, T, W_ih, W_hh, b_ih, b_hh, W_fc, b_fc
    const float* x    = (const float*)d_in[0];
    const float* W_ih = (const float*)d_in[2];
    const float* W_hh = (const float*)d_in[3];
    const float* b_ih = (const float*)d_in[4];
    const float* b_hh = (const float*)d_in[5];
    const float* W_fc = (const float*)d_in[6];
    const float* b_fc = (const float*)d_in[7];
    float* out = (float*)d_out;

    const int B = in_sizes[0] / 32;      // 262144
    const int grid = B / 64;             // 4096 blocks, 64 rows each

    rnn_mfma<<<grid, BLOCK, 0, stream>>>(x, W_ih, W_hh, b_ih, b_hh, W_fc, b_fc, out);
}

// Round 4
// 115.195 us; speedup vs baseline: 1.1436x; 1.0077x over previous
//
#include <hip/hip_runtime.h>

// Elman RNN, B=262144, IN=32, H=16, T=30, OUT=1, fp32 in/out.
// Round 9 (= round 8 resubmit after infra failure, with BLOCK=128 hedge).
// Evidence through r7: VALU-pipe issue in the 30-step loop is the binding
// resource (r6 trans->VALU swap ~ wash; r7 VALU prologue cut -> -23% wall,
// superlinear => issue congestion). Memory 11% of peak, MFMA pipe ~11%.
//  - tanh block rewritten on float2 ext-vectors with pairing U={0,2},
//    V={1,3}: all cross-products become element-wise -> clang lowers to
//    VOP3P v_pk_{add,mul,fma}_f32 (2 fp32 ops / lane / instr on gfx950).
//    19 scalar VALU -> ~12 packed/scalar. BIT-IDENTICAL numerics (same
//    ops, same order; ffp-contract forms the same fma).
//  - BLOCK 256 -> 128 (grid 8192): decouple wave retirement (2-wave barrier
//    instead of 4-wave). NOT 64: CDNA caps ~16 workgroups/CU, so 1-wave
//    blocks would cap occupancy at 16 waves/CU (50%) < measured 62%.
//    128-thread blocks allow 16 WG x 2 waves = 32 waves/CU.
//  - xproj via 6 chained split-precision fp16 MFMAs (r7, verified).
//  - fc head pipelined 2 steps deep, float2 LDS writes (r7).
// Layout invariant (verified rounds 2-4): for 16x16x16 MFMA the B-fragment
// layout == C/D layout, so tanh(acc) repacks elementwise into the next B
// operand — the state stays transposed (S = H^T), never crosses lanes.

#define T_STEPS 30
#define BLOCK   128
#define SCALE   2.8853900817779268f   // 2*log2(e)

typedef _Float16 v4h __attribute__((ext_vector_type(4)));
typedef __fp16   v2fp __attribute__((ext_vector_type(2)));
typedef float    v4f __attribute__((ext_vector_type(4)));
typedef float    v2f __attribute__((ext_vector_type(2)));

struct h4 { v2fp lo, hi; };

static __device__ __forceinline__ v4h pack4(float a, float b, float c, float d) {
    h4 p;
    p.lo = __builtin_amdgcn_cvt_pkrtz(a, b);
    p.hi = __builtin_amdgcn_cvt_pkrtz(c, d);
    return __builtin_bit_cast(v4h, p);
}

__global__ __launch_bounds__(BLOCK, 8) void rnn_mfma(
    const float* __restrict__ x,     // [B, 32]
    const float* __restrict__ W_ih,  // [16, 32]
    const float* __restrict__ W_hh,  // [16, 16]
    const float* __restrict__ b_ih,  // [16]
    const float* __restrict__ b_hh,  // [16]
    const float* __restrict__ W_fc,  // [1, 16]
    const float* __restrict__ b_fc,  // [1]
    float* __restrict__ out)         // [B, 30]
{
    __shared__ float tmp[32 * T_STEPS];   // 32 rows/block x 30 steps

    const int tid  = threadIdx.x;
    const int w    = tid >> 6;        // wave in block (0..1), 16 rows each
    const int lane = tid & 63;
    const int r    = lane & 15;       // MFMA row index (batch row / A-row)
    const int q    = lane >> 4;       // quad
    const int j0   = 4 * q;

    const size_t row = (size_t)blockIdx.x * 32 + (size_t)w * 16 + r;

    // ---- xproj via split-precision MFMA chain.
    // A-frag (m=lane&15, k=4q+e): lane holds SCALE*W_ih[r][kh*16 + 4q+e].
    // B-frag (k=4q+e, n=lane&15): lane holds x[row][kh*16 + 4q+e].
    // C-frag (row=4q+i, col=lane&15): bias SCALE*(b_ih+b_hh)[4q+i].
    v4f xpv;
    {
        const float4 x0 = *(const float4*)(x + row * 32 + 4 * q);
        const float4 x1 = *(const float4*)(x + row * 32 + 16 + 4 * q);
        float4 w0 = *(const float4*)(W_ih + r * 32 + 4 * q);
        float4 w1 = *(const float4*)(W_ih + r * 32 + 16 + 4 * q);
        w0.x *= SCALE; w0.y *= SCALE; w0.z *= SCALE; w0.w *= SCALE;
        w1.x *= SCALE; w1.y *= SCALE; w1.z *= SCALE; w1.w *= SCALE;

        v4h xh0 = pack4(x0.x, x0.y, x0.z, x0.w);
        v4h xh1 = pack4(x1.x, x1.y, x1.z, x1.w);
        v4h wh0 = pack4(w0.x, w0.y, w0.z, w0.w);
        v4h wh1 = pack4(w1.x, w1.y, w1.z, w1.w);
        v4h xl0 = pack4(x0.x - (float)xh0[0], x0.y - (float)xh0[1],
                        x0.z - (float)xh0[2], x0.w - (float)xh0[3]);
        v4h xl1 = pack4(x1.x - (float)xh1[0], x1.y - (float)xh1[1],
                        x1.z - (float)xh1[2], x1.w - (float)xh1[3]);
        v4h wl0 = pack4(w0.x - (float)wh0[0], w0.y - (float)wh0[1],
                        w0.z - (float)wh0[2], w0.w - (float)wh0[3]);
        v4h wl1 = pack4(w1.x - (float)wh1[0], w1.y - (float)wh1[1],
                        w1.z - (float)wh1[2], w1.w - (float)wh1[3]);

        const float4 bi = *(const float4*)(b_ih + j0);
        const float4 bh = *(const float4*)(b_hh + j0);
        v4f c = {SCALE * (bi.x + bh.x), SCALE * (bi.y + bh.y),
                 SCALE * (bi.z + bh.z), SCALE * (bi.w + bh.w)};

        xpv = __builtin_amdgcn_mfma_f32_16x16x16f16(wh0, xh0, c,   0, 0, 0);
        xpv = __builtin_amdgcn_mfma_f32_16x16x16f16(wh1, xh1, xpv, 0, 0, 0);
        xpv = __builtin_amdgcn_mfma_f32_16x16x16f16(wh0, xl0, xpv, 0, 0, 0);
        xpv = __builtin_amdgcn_mfma_f32_16x16x16f16(wh1, xl1, xpv, 0, 0, 0);
        xpv = __builtin_amdgcn_mfma_f32_16x16x16f16(wl0, xh0, xpv, 0, 0, 0);
        xpv = __builtin_amdgcn_mfma_f32_16x16x16f16(wl1, xh1, xpv, 0, 0, 0);
    }

    // ---- W_hh A-fragment in fp16 (RNE): A[m=r][k=4q+i] = SCALE*W_hh[r][4q+i]
    v4h whh;
    {
        float4 wr = *(const float4*)(W_hh + r * 16 + 4 * q);
        whh[0] = (_Float16)(wr.x * SCALE);
        whh[1] = (_Float16)(wr.y * SCALE);
        whh[2] = (_Float16)(wr.z * SCALE);
        whh[3] = (_Float16)(wr.w * SCALE);
    }

    // ---- fc A-fragment (UNSCALED): row0 = fp16(W_fc), row1 = fp16 residual
    v4h afc;
#pragma unroll
    for (int i = 0; i < 4; ++i) {
        float wv = W_fc[4 * q + i];
        _Float16 hi = (_Float16)wv;
        _Float16 lo = (_Float16)(wv - (float)hi);
        afc[i] = (r == 0) ? hi : ((r == 1) ? lo : (_Float16)0.0f);
    }
    const float bfc = b_fc[0];
    const v4f zfc = {(q == 0) ? bfc : 0.0f, 0.0f, 0.0f, 0.0f};

    // ---- state S = H^T in fp16 (B-frag == C/D-frag layout)
    v4h s = {(_Float16)0.0f, (_Float16)0.0f, (_Float16)0.0f, (_Float16)0.0f};

    float* myout = &tmp[(w * 16 + r) * T_STEPS];   // lanes 0..15 write

    const v2f one2  = {1.0f, 1.0f};
    const v2f mtwo2 = {-2.0f, -2.0f};

    v4f fe, fo;   // pipelined fc results (even / odd step)

#pragma unroll
    for (int t = 0; t < T_STEPS; ++t) {
        // preact (pre-scaled) = SCALE*Xp^T + (SCALE*W_hh)*S — one fp16 MFMA
        v4f acc = __builtin_amdgcn_mfma_f32_16x16x16f16(whh, s, xpv, 0, 0, 0);

        // tanh = 1 - 2/(1+e), e = exp2(preact_scaled).
        // Packed dual-fp32 algebra, pairing U={elem0,2}, V={elem1,3}:
        // all cross-products are element-wise -> v_pk_{add,mul,fma}_f32.
        // ONE shared rcp across the 4 denominators (product trick).
        // Bit-identical to the scalar version.
        v2f eU = {__builtin_amdgcn_exp2f(acc[0]), __builtin_amdgcn_exp2f(acc[2])};
        v2f eV = {__builtin_amdgcn_exp2f(acc[1]), __builtin_amdgcn_exp2f(acc[3])};
        v2f dU = eU + one2;                // {d0, d2}
        v2f dV = eV + one2;                // {d1, d3}
        v2f M  = dU * dV;                  // {m01, m23}
        float rr  = __builtin_amdgcn_rcpf(M.x * M.y);
        float r01 = rr * M.y;              // ~ 1/(d0*d1)
        float r23 = rr * M.x;              // ~ 1/(d2*d3)
        v2f Wsw  = {r01, r23};
        v2f invU = Wsw * dV;               // {1/d0, 1/d2}
        v2f invV = Wsw * dU;               // {1/d1, 1/d3}
        v2f hU = mtwo2 * invU + one2;      // {h0, h2}  (pk_fma)
        v2f hV = mtwo2 * invV + one2;      // {h1, h3}

        // repack state: 2 x v_cvt_pkrtz (RTZ, |err| <= 1 ulp ~ 2^-10)
        s = pack4(hU.x, hV.x, hU.y, hV.y);

        // fc head: one MFMA, consumed 1-2 iterations later (waitcnt off the
        // chain); two steps' outputs merge into one float2 LDS write.
        if ((t & 1) == 0) {
            if (t >= 2 && lane < 16) {
                float2 g;
                g.x = fe[0] + fe[1];
                g.y = fo[0] + fo[1];
                *(float2*)(myout + (t - 2)) = g;
            }
            fe = __builtin_amdgcn_mfma_f32_16x16x16f16(afc, s, zfc, 0, 0, 0);
        } else {
            fo = __builtin_amdgcn_mfma_f32_16x16x16f16(afc, s, zfc, 0, 0, 0);
        }
    }
    if (lane < 16) {
        float2 g;
        g.x = fe[0] + fe[1];
        g.y = fo[0] + fo[1];
        *(float2*)(myout + (T_STEPS - 2)) = g;
    }

    __syncthreads();

    // ---- coalesced writeout: block region out[block*32..+32)[0..30) contiguous
    float* oblk = out + (size_t)blockIdx.x * (32 * T_STEPS);
    for (int idx = tid; idx < 32 * T_STEPS; idx += BLOCK)
        oblk[idx] = tmp[idx];
}

extern "C" void kernel_launch(void* const* d_in, const int* in_sizes, int n_in,
                              void* d_out, int out_size, void* d_ws, size_t ws_size,
                              hipStream_t stream) {
    // inputs: x, T, W_ih, W_hh, b_ih, b_hh, W_fc, b_fc
    const float* x    = (const float*)d_in[0];
    const float* W_ih = (const float*)d_in[2];
    const float* W_hh = (const float*)d_in[3];
    const float* b_ih = (const float*)d_in[4];
    const float* b_hh = (const float*)d_in[5];
    const float* W_fc = (const float*)d_in[6];
    const float* b_fc = (const float*)d_in[7];
    float* out = (float*)d_out;

    const int B = in_sizes[0] / 32;      // 262144
    const int grid = B / 32;             // 8192 blocks, 32 rows each

    rnn_mfma<<<grid, BLOCK, 0, stream>>>(x, W_ih, W_hh, b_ih, b_hh, W_fc, b_fc, out);
}